// Round 12
// baseline (151.227 us; speedup 1.0000x reference)
//
#include <hip/hip_runtime.h>
#include <math.h>

#define T_TOK 4096
#define A_DIM 1024
#define E_DIM 512
#define N_SPAN 32768
#define W_MAX 10
#define HID 150
#define FD 20

#define PR  160             // P row stride (bf16 elems); cols 150..159 zero
#define KP2 160             // padded K/N for the 150x150 layers

// ---- workspace layout (float offsets) ----
// attns: [0, 4096)
// Pb:    [4096, 1314816)    = 2,621,440 ushorts (4 x 4096 x 160: P0..P3)
// wpack: [1314816, 1627856) = 626,080 ushorts   (~6.5 MB total)
#define WS_ATTNS 0
#define WS_PB    4096
#define WS_WPACK 1314816
// Pb ushort offsets
#define PB_P0 0
#define PB_P1 655360
#define PB_P2 1310720
#define PB_P3 1966080
// wpack ushort offsets
//   ST: [3 gidx][2 ngrp][32 c][2560]  (chunk-contiguous, XOR-swizzled)
//   V : [2 ngrp][16 c][2560]
//   A2/S2: [160 n][160 k] n-major;  WE1: [9][160]
#define WP_ST  0
#define WP_V   491520
#define WP_A2  573440
#define WP_S2  599040
#define WP_WE1 624640
#define WP_TOTAL 626080

typedef short  bf16x8 __attribute__((ext_vector_type(8)));
typedef float  f32x4  __attribute__((ext_vector_type(4)));

__device__ __forceinline__ float4 ld4(const float* p) { return *(const float4*)p; }

__device__ __forceinline__ unsigned short f2bf(float f) {
    unsigned u = __float_as_uint(f);
    unsigned r = u + 0x7fffu + ((u >> 16) & 1u);   // RNE
    return (unsigned short)(r >> 16);
}
__device__ __forceinline__ float bf2f(short s) {
    return __uint_as_float(((unsigned)(unsigned short)s) << 16);
}
__device__ __forceinline__ bf16x8 cvt_regs(const float4* a) {
    bf16x8 f;
    f[0] = (short)f2bf(a[0].x); f[1] = (short)f2bf(a[0].y);
    f[2] = (short)f2bf(a[0].z); f[3] = (short)f2bf(a[0].w);
    f[4] = (short)f2bf(a[1].x); f[5] = (short)f2bf(a[1].y);
    f[6] = (short)f2bf(a[1].z); f[7] = (short)f2bf(a[1].w);
    return f;
}

// async global->LDS, 16 B/lane; LDS dst = wave-uniform base + lane*16
typedef const __attribute__((address_space(1))) unsigned int as1_u32;
typedef __attribute__((address_space(3))) unsigned int as3_u32;
__device__ __forceinline__ void dma16(const void* g, void* l) {
    __builtin_amdgcn_global_load_lds((as1_u32*)g, (as3_u32*)l, 16, 0, 0);
}
template<int N> __device__ __forceinline__ void waitv() {
    asm volatile("s_waitcnt vmcnt(%0)" :: "n"(N) : "memory");
}

// ---------------------------------------------------------------------------
// Prepack (dst-linear, coalesced writes):
//  ST/V -> chunk-contiguous swizzled: within a 2560-ushort chunk, element
//  d: n=d>>5, qsw=(d&31)>>3, off=d&7; stores k-piece q = qsw ^ ((n>>1)&3).
//  A2/S2 -> n-major [n][160]; WE1[9][160] = width_emb @ Ws1[2560:].
// ---------------------------------------------------------------------------
__global__ __launch_bounds__(256) void prepack_kernel(
    const float* __restrict__ Wa1, const float* __restrict__ Ws1,
    const float* __restrict__ Wa2, const float* __restrict__ Ws2,
    const float* __restrict__ width_emb, unsigned short* __restrict__ wp)
{
    int idx = blockIdx.x * 256 + threadIdx.x;
    if (idx >= WP_TOTAL) return;
    float v = 0.f;
    if (idx < WP_V) {                               // ST: 3 x 2 x 32 x 2560
        int gidx = idx / 163840, r = idx % 163840;
        int ngrp = r / 81920, r2 = r % 81920;
        int c = r2 / 2560, d = r2 % 2560;
        int n = d >> 5, qsw = (d >> 3) & 3, off = d & 7;
        int q = qsw ^ ((n >> 1) & 3);
        int k = c * 32 + q * 8 + off;
        int gn = ngrp * 80 + n;
        const float* W = (gidx == 0) ? Wa1 : Ws1 + (size_t)(gidx - 1) * 1024 * HID;
        if (gn < HID) v = W[(size_t)k * HID + gn];
    } else if (idx < WP_A2) {                       // V: 2 x 16 x 2560
        int r = idx - WP_V;
        int ngrp = r / 40960, r2 = r % 40960;
        int c = r2 / 2560, d = r2 % 2560;
        int n = d >> 5, qsw = (d >> 3) & 3, off = d & 7;
        int q = qsw ^ ((n >> 1) & 3);
        int k = c * 32 + q * 8 + off;
        int gn = ngrp * 80 + n;
        if (gn < HID) v = Ws1[(size_t)(2048 + k) * HID + gn];
    } else if (idx < WP_S2) {                       // Wa2 [n][160]
        int e = idx - WP_A2;
        int n = e / KP2, k = e % KP2;
        if (n < HID && k < HID) v = Wa2[(size_t)k * HID + n];
    } else if (idx < WP_WE1) {                      // Ws2 [n][160]
        int e = idx - WP_S2;
        int n = e / KP2, k = e % KP2;
        if (n < HID && k < HID) v = Ws2[(size_t)k * HID + n];
    } else {                                        // WE1 [9][160]
        int e = idx - WP_WE1;
        int b = e / KP2, n = e % KP2;
        if (n < HID)
            for (int k = 0; k < FD; ++k)
                v = fmaf(width_emb[b * FD + k], Ws1[(size_t)(2560 + k) * HID + n], v);
    }
    wp[idx] = f2bf(v);
}

// ---------------------------------------------------------------------------
// Single-wave DMA-pipelined 32x80 GEMM strip (M=32: 2 m-tiles/wave).
// Triple-buffered LDS B; 3-slot register A (4 x float4 per slot).
// Per chunk: 5 B-DMA + 4 A-loads = 9 vmcnt ops; steady-state waitv<18>
// (chunks c+1,c+2 in flight), tails 9/0. No barriers.
// ---------------------------------------------------------------------------
template<int NC>
__device__ __forceinline__ void gemm_dma(
    const float* __restrict__ aPtr,            // row m0+l15, K-stride = 32*NC
    const unsigned short* __restrict__ srcB,
    unsigned short (*__restrict__ bufB)[2560],
    int lane, int l15, int quad, f32x4 (&acc)[2][5])
{
    constexpr int K = NC * 32;
    const int swz = (quad ^ ((l15 >> 1) & 3)) * 8;
    float4 aR[3][4];
#define DMAB(c) { _Pragma("unroll")                                          \
        for (int i = 0; i < 5; ++i)                                          \
            dma16(srcB + (size_t)(c) * 2560 + i * 512 + lane * 8,            \
                  &bufB[(c) % 3][i * 512]); }
#define LDA(c) { aR[(c) % 3][0] = ld4(aPtr + (c) * 32);                      \
                 aR[(c) % 3][1] = ld4(aPtr + (c) * 32 + 4);                  \
                 aR[(c) % 3][2] = ld4(aPtr + 16 * K + (c) * 32);             \
                 aR[(c) % 3][3] = ld4(aPtr + 16 * K + (c) * 32 + 4); }
    DMAB(0); LDA(0);
    DMAB(1); LDA(1);
#pragma unroll
    for (int c = 0; c < NC; ++c) {
        if (c + 2 < NC) { DMAB(c + 2); LDA(c + 2); }
        if (c + 2 < NC)      waitv<18>();
        else if (c + 1 < NC) waitv<9>();
        else                 waitv<0>();
        bf16x8 af0 = cvt_regs(&aR[c % 3][0]);
        bf16x8 af1 = cvt_regs(&aR[c % 3][2]);
        const unsigned short* bb = &bufB[c % 3][0];
#pragma unroll
        for (int t = 0; t < 5; ++t) {
            bf16x8 bf = *(const bf16x8*)(bb + t * 512 + l15 * 32 + swz);
            acc[0][t] = __builtin_amdgcn_mfma_f32_16x16x32_bf16(af0, bf, acc[0][t], 0, 0, 0);
            acc[1][t] = __builtin_amdgcn_mfma_f32_16x16x32_bf16(af1, bf, acc[1][t], 0, 0, 0);
        }
    }
#undef DMAB
#undef LDA
}

// ---------------------------------------------------------------------------
// Token kernel: 1024 blocks x 64 threads (1 wave each), 15 KB LDS.
//   task <  768 : states x {Wa1,Ws1a,Ws1b}, M=32 -> P0/P1/P2 (K=1024, NC=32)
//   task >= 768 : embeds x V,               M=32 -> P3       (K=512,  NC=16)
// ---------------------------------------------------------------------------
__global__ __launch_bounds__(64) void token_kernel(
    const float* __restrict__ states, const float* __restrict__ embeds,
    const unsigned short* __restrict__ wp, unsigned short* __restrict__ Pb)
{
    __shared__ __align__(16) unsigned short bufB[3][2560];   // 15 KB

    const int lane = threadIdx.x, l15 = lane & 15, quad = lane >> 4;
    const int task = blockIdx.x;

    f32x4 acc[2][5];
#pragma unroll
    for (int mt = 0; mt < 2; ++mt)
#pragma unroll
        for (int t = 0; t < 5; ++t)
#pragma unroll
            for (int i = 0; i < 4; ++i) acc[mt][t][i] = 0.f;

    int m0, gidx, ngrp;
    if (task < 768) {
        m0 = (task / 6) * 32;
        const int sub = task % 6;
        gidx = sub >> 1;                 // 0:Wa1->P0, 1:Ws1a->P1, 2:Ws1b->P2
        ngrp = sub & 1;
        const float* aPtr = states + (size_t)(m0 + l15) * A_DIM + quad * 8;
        const unsigned short* srcB = wp + WP_ST + gidx * 163840 + ngrp * 81920;
        gemm_dma<32>(aPtr, srcB, bufB, lane, l15, quad, acc);
    } else {
        const int e = task - 768;
        m0 = (e >> 1) * 32;
        ngrp = e & 1;
        gidx = 3;                        // V -> P3
        const float* aPtr = embeds + (size_t)(m0 + l15) * E_DIM + quad * 8;
        const unsigned short* srcB = wp + WP_V + ngrp * 40960;
        gemm_dma<16>(aPtr, srcB, bufB, lane, l15, quad, acc);
    }

    unsigned short* Pg = Pb + (size_t)gidx * 655360;
#pragma unroll
    for (int mt = 0; mt < 2; ++mt) {
        const int rowb = m0 + mt * 16 + quad * 4;
#pragma unroll
        for (int t = 0; t < 5; ++t) {
            const int col = ngrp * 80 + t * 16 + l15;
#pragma unroll
            for (int i = 0; i < 4; ++i)
                Pg[(size_t)(rowb + i) * PR + col] =
                    (col < HID) ? f2bf(acc[mt][t][i]) : (unsigned short)0;
        }
    }
}

// ---------------------------------------------------------------------------
// Attn tail: one wave per 16 tokens, barrier-free. h1 = relu(P0 + ba1) as
// A-frags from bf16 P0; layer2 MFMA vs packed Wa2; layer3 shuffle-reduce.
// ---------------------------------------------------------------------------
__global__ __launch_bounds__(64) void attn_tail_kernel(
    const unsigned short* __restrict__ P0, const float* __restrict__ ba1,
    const unsigned short* __restrict__ wp, const float* __restrict__ ba2,
    const float* __restrict__ Wa3, const float* __restrict__ ba3,
    float* __restrict__ attns)
{
    const int t0 = blockIdx.x * 16;
    const int lane = threadIdx.x, l15 = lane & 15, quad = lane >> 4;

    f32x4 acc[10];
#pragma unroll
    for (int nt = 0; nt < 10; ++nt)
#pragma unroll
        for (int i = 0; i < 4; ++i) acc[nt][i] = 0.f;

    const unsigned short* prow = P0 + (size_t)(t0 + l15) * PR;
    const unsigned short* bb = wp + WP_A2 + l15 * KP2 + quad * 8;

#pragma unroll
    for (int c = 0; c < 5; ++c) {
        const int k0 = c * 32;
        const int kk = k0 + quad * 8;
        bf16x8 raw = *(const bf16x8*)(prow + kk);
        bf16x8 af;
#pragma unroll
        for (int j = 0; j < 8; ++j) {
            const float b = (kk + j < HID) ? ba1[kk + j] : 0.f;
            af[j] = (short)f2bf(fmaxf(bf2f(raw[j]) + b, 0.f));
        }
#pragma unroll
        for (int nt = 0; nt < 10; ++nt) {
            bf16x8 bf = *(const bf16x8*)(bb + nt * 16 * KP2 + k0);
            acc[nt] = __builtin_amdgcn_mfma_f32_16x16x32_bf16(af, bf, acc[nt], 0, 0, 0);
        }
    }

    float sc[4] = {0.f, 0.f, 0.f, 0.f};
#pragma unroll
    for (int nt = 0; nt < 10; ++nt) {
        const int col = nt * 16 + l15;
        const float w3 = (col < HID) ? Wa3[col] : 0.f;
        const float b2 = (col < HID) ? ba2[col] : 0.f;
#pragma unroll
        for (int i = 0; i < 4; ++i)
            sc[i] = fmaf(fmaxf(acc[nt][i] + b2, 0.f), w3, sc[i]);
    }
#pragma unroll
    for (int off = 8; off >= 1; off >>= 1)
#pragma unroll
        for (int i = 0; i < 4; ++i) sc[i] += __shfl_down(sc[i], off, 16);
    if (l15 == 0) {
        const float b3 = ba3[0];
#pragma unroll
        for (int i = 0; i < 4; ++i) attns[t0 + quad * 4 + i] = sc[i] + b3;
    }
}

// ---------------------------------------------------------------------------
// Span kernel: 32 spans/block, grid 1024. Gather-combine from bf16 P
// (XCD-L2 resident) -> h1 bf16 in LDS; layer2 MFMA; layer3 shuffle-reduce.
// ---------------------------------------------------------------------------
__global__ __launch_bounds__(256) void span_kernel(
    const unsigned short* __restrict__ Pb, const float* __restrict__ attns,
    const unsigned short* __restrict__ wp,
    const int* __restrict__ span_starts, const int* __restrict__ span_widths,
    const float* __restrict__ bs1, const float* __restrict__ bs2,
    const float* __restrict__ Ws3, const float* __restrict__ bs3,
    float* __restrict__ out)
{
    __shared__ unsigned short sHb[32][168];
    __shared__ float s_wgt[32][W_MAX];
    __shared__ int s_st[32], s_wd[32], s_bin[32];
    __shared__ float sPart[4][32];
    __shared__ float sb1[KP2];

    const int tid = threadIdx.x;
    const int n0s = blockIdx.x * 32;

    if (tid < KP2) sb1[tid] = (tid < HID) ? bs1[tid] : 0.f;
    if (tid < 32) {
        int st = span_starts[n0s + tid], wd = span_widths[n0s + tid];
        s_st[tid] = st; s_wd[tid] = wd;
        s_bin[tid] = (wd >= 1) + (wd >= 2) + (wd >= 3) + (wd >= 4) +
                     (wd >= 8) + (wd >= 16) + (wd >= 32) + (wd >= 64);
        float lg[W_MAX];
        float m = -1e30f;
#pragma unroll
        for (int w = 0; w < W_MAX; ++w)
            if (w < wd) { float a = attns[st + w]; lg[w] = a; m = fmaxf(m, a); }
        float sum = 0.f;
#pragma unroll
        for (int w = 0; w < W_MAX; ++w) {
            float e = (w < wd) ? __expf(lg[w] - m) : 0.f;
            lg[w] = e; sum += e;
        }
        float inv = 1.f / sum;
#pragma unroll
        for (int w = 0; w < W_MAX; ++w) s_wgt[tid][w] = lg[w] * inv;
    }
    __syncthreads();

    // gather-combine: 8 lanes/span, bf16x8 chunks
    {
        const unsigned short* P1b = Pb + PB_P1;
        const unsigned short* P2b = Pb + PB_P2;
        const unsigned short* P3b = Pb + PB_P3;
        const unsigned short* WEb = wp + WP_WE1;
        const int s = tid >> 3, jl = tid & 7;
        const int st = s_st[s], wd = s_wd[s];
        const size_t rs = (size_t)st * PR;
        const size_t re = (size_t)(st + wd - 1) * PR;
        const size_t rb = (size_t)s_bin[s] * PR;
        for (int c = jl; c < 20; c += 8) {
            const int j = c * 8;
            bf16x8 u1 = *(const bf16x8*)(P1b + rs + j);
            bf16x8 u2 = *(const bf16x8*)(P2b + re + j);
            bf16x8 uw = *(const bf16x8*)(WEb + rb + j);
            float acc[8];
#pragma unroll
            for (int i = 0; i < 8; ++i)
                acc[i] = bf2f(u1[i]) + bf2f(u2[i]) + bf2f(uw[i]) + sb1[j + i];
#pragma unroll
            for (int w = 0; w < W_MAX; ++w) {
                if (w < wd) {
                    float wt = s_wgt[s][w];
                    bf16x8 uv = *(const bf16x8*)(P3b + rs + (size_t)w * PR + j);
#pragma unroll
                    for (int i = 0; i < 8; ++i)
                        acc[i] = fmaf(wt, bf2f(uv[i]), acc[i]);
                }
            }
            bf16x8 pk;
#pragma unroll
            for (int i = 0; i < 8; ++i) pk[i] = (short)f2bf(fmaxf(acc[i], 0.f));
            *(bf16x8*)&sHb[s][j] = pk;
        }
    }
    __syncthreads();

    // layer2 MFMA: M=32 (2 m-tiles), N=160 (tiles 3,3,2,2 over waves)
    const int wv = tid >> 6, lane = tid & 63, l15 = lane & 15, quad = lane >> 4;
    const int nb = (wv < 2) ? wv * 3 : 6 + (wv - 2) * 2;
    const int cnt = (wv < 2) ? 3 : 2;

    f32x4 a2[2][3];
#pragma unroll
    for (int mt = 0; mt < 2; ++mt)
#pragma unroll
        for (int t = 0; t < 3; ++t)
#pragma unroll
            for (int i = 0; i < 4; ++i) a2[mt][t][i] = 0.f;

#pragma unroll
    for (int c = 0; c < 5; ++c) {
        int k0 = c * 32;
        bf16x8 af0 = *(const bf16x8*)&sHb[l15][k0 + quad * 8];
        bf16x8 af1 = *(const bf16x8*)&sHb[16 + l15][k0 + quad * 8];
#pragma unroll
        for (int t = 0; t < 3; ++t) {
            if (t < cnt) {
                bf16x8 b = *(const bf16x8*)(wp + WP_S2 +
                            (size_t)((nb + t) * 16 + l15) * KP2 + k0 + quad * 8);
                a2[0][t] = __builtin_amdgcn_mfma_f32_16x16x32_bf16(af0, b, a2[0][t], 0, 0, 0);
                a2[1][t] = __builtin_amdgcn_mfma_f32_16x16x32_bf16(af1, b, a2[1][t], 0, 0, 0);
            }
        }
    }

    float sc[2][4];
#pragma unroll
    for (int mt = 0; mt < 2; ++mt)
#pragma unroll
        for (int i = 0; i < 4; ++i) sc[mt][i] = 0.f;
#pragma unroll
    for (int t = 0; t < 3; ++t) {
        if (t < cnt) {
            int col = (nb + t) * 16 + l15;
            float w3 = (col < HID) ? Ws3[col] : 0.f;
            float b2 = (col < HID) ? bs2[col] : 0.f;
#pragma unroll
            for (int mt = 0; mt < 2; ++mt)
#pragma unroll
                for (int i = 0; i < 4; ++i)
                    sc[mt][i] = fmaf(fmaxf(a2[mt][t][i] + b2, 0.f), w3, sc[mt][i]);
        }
    }
#pragma unroll
    for (int off = 8; off >= 1; off >>= 1)
#pragma unroll
        for (int mt = 0; mt < 2; ++mt)
#pragma unroll
            for (int i = 0; i < 4; ++i)
                sc[mt][i] += __shfl_down(sc[mt][i], off, 16);
    if (l15 == 0) {
#pragma unroll
        for (int mt = 0; mt < 2; ++mt)
#pragma unroll
            for (int i = 0; i < 4; ++i)
                sPart[wv][mt * 16 + quad * 4 + i] = sc[mt][i];
    }
    __syncthreads();
    if (tid < 32)
        out[n0s + tid] = sPart[0][tid] + sPart[1][tid] + sPart[2][tid] +
                         sPart[3][tid] + bs3[0];
}

// ---------------------------------------------------------------------------
extern "C" void kernel_launch(void* const* d_in, const int* in_sizes, int n_in,
                              void* d_out, int out_size, void* d_ws, size_t ws_size,
                              hipStream_t stream)
{
    const float* states      = (const float*)d_in[0];
    const float* embeds      = (const float*)d_in[1];
    const int*   span_starts = (const int*)d_in[2];
    const int*   span_widths = (const int*)d_in[3];
    const float* Wa1 = (const float*)d_in[4];
    const float* ba1 = (const float*)d_in[5];
    const float* Wa2 = (const float*)d_in[6];
    const float* ba2 = (const float*)d_in[7];
    const float* Wa3 = (const float*)d_in[8];
    const float* ba3 = (const float*)d_in[9];
    const float* width_emb = (const float*)d_in[10];
    const float* Ws1 = (const float*)d_in[11];
    const float* bs1 = (const float*)d_in[12];
    const float* Ws2 = (const float*)d_in[13];
    const float* bs2 = (const float*)d_in[14];
    const float* Ws3 = (const float*)d_in[15];
    const float* bs3 = (const float*)d_in[16];
    float* out = (float*)d_out;

    float* ws    = (float*)d_ws;
    float* attns = ws + WS_ATTNS;
    unsigned short* Pb    = (unsigned short*)(ws + WS_PB);
    unsigned short* wpack = (unsigned short*)(ws + WS_WPACK);

    hipLaunchKernelGGL(prepack_kernel, dim3((WP_TOTAL + 255) / 256), dim3(256), 0, stream,
                       Wa1, Ws1, Wa2, Ws2, width_emb, wpack);
    hipLaunchKernelGGL(token_kernel, dim3(1024), dim3(64), 0, stream,
                       states, embeds, wpack, Pb);
    hipLaunchKernelGGL(attn_tail_kernel, dim3(T_TOK / 16), dim3(64), 0, stream,
                       Pb + PB_P0, ba1, wpack, ba2, Wa3, ba3, attns);
    hipLaunchKernelGGL(span_kernel, dim3(N_SPAN / 32), dim3(256), 0, stream,
                       Pb, attns, wpack, span_starts, span_widths,
                       bs1, bs2, Ws3, bs3, out);
}

// Round 13
// 150.006 us; speedup vs baseline: 1.0081x; 1.0081x over previous
//
#include <hip/hip_runtime.h>
#include <math.h>

#define T_TOK 4096
#define A_DIM 1024
#define E_DIM 512
#define N_SPAN 32768
#define W_MAX 10
#define HID 150
#define FD 20

#define PR  160             // P row stride (bf16 elems); cols 150..159 zero
#define KP2 160             // padded K/N for the 150x150 layers

// ---- workspace layout (float offsets) ----
// attns: [0, 4096)
// Pb:    [4096, 1314816)       4 x 4096 x 160 ushort
// wpack: [1314816, 1627856)    626,080 ushort
// Sb:    [1627856, 3725008)    4096 x 1024 bf16 (swizzled piece layout)
// Eb:    [3725008, 4773584)    4096 x 512 bf16  (~19.1 MB total)
#define WS_ATTNS 0
#define WS_PB    4096
#define WS_WPACK 1314816
#define WS_SB    1627856
#define WS_EB    3725008
// Pb ushort offsets
#define PB_P0 0
#define PB_P1 655360
#define PB_P2 1310720
#define PB_P3 1966080
// wpack ushort offsets
//   ST: [3 gidx][2 ngrp][32 c][2560]  (chunk-contiguous, XOR-swizzled)
//   V : [2 ngrp][16 c][2560]
//   A2/S2: [160 n][160 k] n-major;  WE1: [9][160]
#define WP_ST  0
#define WP_V   491520
#define WP_A2  573440
#define WP_S2  599040
#define WP_WE1 624640
#define WP_TOTAL 626080
#define SB_PIECES 524288     // 4096*1024/8
#define EB_PIECES 262144     // 4096*512/8
#define PK_ITEMS (WP_TOTAL + SB_PIECES + EB_PIECES)

typedef short  bf16x8 __attribute__((ext_vector_type(8)));
typedef float  f32x4  __attribute__((ext_vector_type(4)));

__device__ __forceinline__ float4 ld4(const float* p) { return *(const float4*)p; }

__device__ __forceinline__ unsigned short f2bf(float f) {
    unsigned u = __float_as_uint(f);
    unsigned r = u + 0x7fffu + ((u >> 16) & 1u);   // RNE
    return (unsigned short)(r >> 16);
}
__device__ __forceinline__ float bf2f(short s) {
    return __uint_as_float(((unsigned)(unsigned short)s) << 16);
}
__device__ __forceinline__ bf16x8 cvt_frag(const float* p) {
    float4 u = ld4(p), v = ld4(p + 4);
    bf16x8 f;
    f[0] = (short)f2bf(u.x); f[1] = (short)f2bf(u.y);
    f[2] = (short)f2bf(u.z); f[3] = (short)f2bf(u.w);
    f[4] = (short)f2bf(v.x); f[5] = (short)f2bf(v.y);
    f[6] = (short)f2bf(v.z); f[7] = (short)f2bf(v.w);
    return f;
}

// async global->LDS, 16 B/lane; LDS dst = wave-uniform base + lane*16
typedef const __attribute__((address_space(1))) unsigned int as1_u32;
typedef __attribute__((address_space(3))) unsigned int as3_u32;
__device__ __forceinline__ void dma16(const void* g, void* l) {
    __builtin_amdgcn_global_load_lds((as1_u32*)g, (as3_u32*)l, 16, 0, 0);
}
template<int N> __device__ __forceinline__ void waitv() {
    asm volatile("s_waitcnt vmcnt(%0)" :: "n"(N) : "memory");
}

// ---------------------------------------------------------------------------
// Prepack (dst-linear, coalesced writes):
//  (1) weights -> chunk-contiguous swizzled ST/V + n-major A2/S2 + WE1;
//  (2) states/embeds -> bf16 Sb/Eb in the same swizzled piece layout
//      ([mtile][chunk][m 16 x qsw 4 x 8], piece (m,q) at qsw=q^((m>>1)&3))
//      so the token kernel's A arrives via the same DMA pipe, cvt-free.
// ---------------------------------------------------------------------------
__global__ __launch_bounds__(256) void prepack_kernel(
    const float* __restrict__ states, const float* __restrict__ embeds,
    const float* __restrict__ Wa1, const float* __restrict__ Ws1,
    const float* __restrict__ Wa2, const float* __restrict__ Ws2,
    const float* __restrict__ width_emb,
    unsigned short* __restrict__ wp, unsigned short* __restrict__ Sb,
    unsigned short* __restrict__ Eb)
{
    int idx = blockIdx.x * 256 + threadIdx.x;
    if (idx >= PK_ITEMS) return;
    if (idx < WP_TOTAL) {
        float v = 0.f;
        if (idx < WP_V) {                               // ST: 3 x 2 x 32 x 2560
            int gidx = idx / 163840, r = idx % 163840;
            int ngrp = r / 81920, r2 = r % 81920;
            int c = r2 / 2560, d = r2 % 2560;
            int n = d >> 5, qsw = (d >> 3) & 3, off = d & 7;
            int q = qsw ^ ((n >> 1) & 3);
            int k = c * 32 + q * 8 + off;
            int gn = ngrp * 80 + n;
            const float* W = (gidx == 0) ? Wa1 : Ws1 + (size_t)(gidx - 1) * 1024 * HID;
            if (gn < HID) v = W[(size_t)k * HID + gn];
        } else if (idx < WP_A2) {                       // V: 2 x 16 x 2560
            int r = idx - WP_V;
            int ngrp = r / 40960, r2 = r % 40960;
            int c = r2 / 2560, d = r2 % 2560;
            int n = d >> 5, qsw = (d >> 3) & 3, off = d & 7;
            int q = qsw ^ ((n >> 1) & 3);
            int k = c * 32 + q * 8 + off;
            int gn = ngrp * 80 + n;
            if (gn < HID) v = Ws1[(size_t)(2048 + k) * HID + gn];
        } else if (idx < WP_S2) {                       // Wa2 [n][160]
            int e = idx - WP_A2;
            int n = e / KP2, k = e % KP2;
            if (n < HID && k < HID) v = Wa2[(size_t)k * HID + n];
        } else if (idx < WP_WE1) {                      // Ws2 [n][160]
            int e = idx - WP_S2;
            int n = e / KP2, k = e % KP2;
            if (n < HID && k < HID) v = Ws2[(size_t)k * HID + n];
        } else {                                        // WE1 [9][160]
            int e = idx - WP_WE1;
            int b = e / KP2, n = e % KP2;
            if (n < HID)
                for (int k = 0; k < FD; ++k)
                    v = fmaf(width_emb[b * FD + k], Ws1[(size_t)(2560 + k) * HID + n], v);
        }
        wp[idx] = f2bf(v);
    } else if (idx < WP_TOTAL + SB_PIECES) {            // Sb piece (8 elems)
        int p = idx - WP_TOTAL;
        int mb = p >> 11, r = p & 2047;                 // 2048 pieces per 16-row tile
        int c = r >> 6, d8 = r & 63;
        int m = d8 >> 2, qsw = d8 & 3;
        int q = qsw ^ ((m >> 1) & 3);
        const float* src = states + (size_t)(mb * 16 + m) * A_DIM + c * 32 + q * 8;
        *(bf16x8*)(Sb + (size_t)p * 8) = cvt_frag(src);
    } else {                                            // Eb piece
        int p = idx - WP_TOTAL - SB_PIECES;
        int mb = p >> 10, r = p & 1023;                 // 1024 pieces per tile
        int c = r >> 6, d8 = r & 63;
        int m = d8 >> 2, qsw = d8 & 3;
        int q = qsw ^ ((m >> 1) & 3);
        const float* src = embeds + (size_t)(mb * 16 + m) * E_DIM + c * 32 + q * 8;
        *(bf16x8*)(Eb + (size_t)p * 8) = cvt_frag(src);
    }
}

// ---------------------------------------------------------------------------
// Single-wave DMA-pipelined 16x80 GEMM strip: B AND A both staged by DMA
// (6 ops/chunk), triple-buffered LDS. K-loop has zero global loads and zero
// cvt VALU: 6 ds_read_b128 + 5 MFMA per chunk. Steady waitv<12>, tails 6/0.
// ---------------------------------------------------------------------------
template<int NC>
__device__ __forceinline__ void gemm_dma(
    const unsigned short* __restrict__ srcA, const unsigned short* __restrict__ srcB,
    unsigned short (*__restrict__ bufB)[2560], unsigned short (*__restrict__ bufA)[512],
    int lane, int l15, int quad, f32x4 (&acc)[5])
{
    const int swz = (quad ^ ((l15 >> 1) & 3)) * 8;
    const int bl = l15 * 32 + swz;
#define DMAC(c) { _Pragma("unroll")                                          \
        for (int i = 0; i < 5; ++i)                                          \
            dma16(srcB + (size_t)(c) * 2560 + i * 512 + lane * 8,            \
                  &bufB[(c) % 3][i * 512]);                                  \
        dma16(srcA + (size_t)(c) * 512 + lane * 8, &bufA[(c) % 3][0]); }
    DMAC(0);
    DMAC(1);
#pragma unroll
    for (int c = 0; c < NC; ++c) {
        if (c + 2 < NC) DMAC(c + 2);
        if (c + 2 < NC)      waitv<12>();
        else if (c + 1 < NC) waitv<6>();
        else                 waitv<0>();
        bf16x8 af = *(const bf16x8*)(&bufA[c % 3][0] + bl);
        const unsigned short* bb = &bufB[c % 3][0];
#pragma unroll
        for (int t = 0; t < 5; ++t) {
            bf16x8 bf = *(const bf16x8*)(bb + t * 512 + bl);
            acc[t] = __builtin_amdgcn_mfma_f32_16x16x32_bf16(af, bf, acc[t], 0, 0, 0);
        }
    }
#undef DMAC
}

// ---------------------------------------------------------------------------
// Token kernel: 2048 blocks x 64 threads (1 wave each), 18 KB LDS.
//   task <  1536 : Sb x {Wa1,Ws1a,Ws1b} -> P0/P1/P2 (K=1024, NC=32)
//   task >= 1536 : Eb x V               -> P3       (K=512,  NC=16)
// ---------------------------------------------------------------------------
__global__ __launch_bounds__(64) void token_kernel(
    const unsigned short* __restrict__ Sb, const unsigned short* __restrict__ Eb,
    const unsigned short* __restrict__ wp, unsigned short* __restrict__ Pb)
{
    __shared__ __align__(16) unsigned short bufB[3][2560];   // 15 KB
    __shared__ __align__(16) unsigned short bufA[3][512];    //  3 KB

    const int lane = threadIdx.x, l15 = lane & 15, quad = lane >> 4;
    const int task = blockIdx.x;

    f32x4 acc[5];
#pragma unroll
    for (int t = 0; t < 5; ++t)
#pragma unroll
        for (int i = 0; i < 4; ++i) acc[t][i] = 0.f;

    int m0, gidx, ngrp;
    if (task < 1536) {
        const int mb = task / 6;
        m0 = mb * 16;
        const int sub = task % 6;
        gidx = sub >> 1;                 // 0:Wa1->P0, 1:Ws1a->P1, 2:Ws1b->P2
        ngrp = sub & 1;
        const unsigned short* srcA = Sb + (size_t)mb * 16384;
        const unsigned short* srcB = wp + WP_ST + gidx * 163840 + ngrp * 81920;
        gemm_dma<32>(srcA, srcB, bufB, bufA, lane, l15, quad, acc);
    } else {
        const int e = task - 1536;
        const int mb = e >> 1;
        m0 = mb * 16;
        ngrp = e & 1;
        gidx = 3;                        // V -> P3
        const unsigned short* srcA = Eb + (size_t)mb * 8192;
        const unsigned short* srcB = wp + WP_V + ngrp * 40960;
        gemm_dma<16>(srcA, srcB, bufB, bufA, lane, l15, quad, acc);
    }

    unsigned short* Pg = Pb + (size_t)gidx * 655360;
#pragma unroll
    for (int t = 0; t < 5; ++t) {
        const int col = ngrp * 80 + t * 16 + l15;
#pragma unroll
        for (int i = 0; i < 4; ++i)
            Pg[(size_t)(m0 + quad * 4 + i) * PR + col] =
                (col < HID) ? f2bf(acc[t][i]) : (unsigned short)0;
    }
}

// ---------------------------------------------------------------------------
// Attn tail: one wave per 16 tokens, barrier-free. h1 = relu(P0 + ba1) as
// A-frags from bf16 P0; layer2 MFMA vs packed Wa2; layer3 shuffle-reduce.
// ---------------------------------------------------------------------------
__global__ __launch_bounds__(64) void attn_tail_kernel(
    const unsigned short* __restrict__ P0, const float* __restrict__ ba1,
    const unsigned short* __restrict__ wp, const float* __restrict__ ba2,
    const float* __restrict__ Wa3, const float* __restrict__ ba3,
    float* __restrict__ attns)
{
    const int t0 = blockIdx.x * 16;
    const int lane = threadIdx.x, l15 = lane & 15, quad = lane >> 4;

    f32x4 acc[10];
#pragma unroll
    for (int nt = 0; nt < 10; ++nt)
#pragma unroll
        for (int i = 0; i < 4; ++i) acc[nt][i] = 0.f;

    const unsigned short* prow = P0 + (size_t)(t0 + l15) * PR;
    const unsigned short* bb = wp + WP_A2 + l15 * KP2 + quad * 8;

#pragma unroll
    for (int c = 0; c < 5; ++c) {
        const int k0 = c * 32;
        const int kk = k0 + quad * 8;
        bf16x8 raw = *(const bf16x8*)(prow + kk);
        bf16x8 af;
#pragma unroll
        for (int j = 0; j < 8; ++j) {
            const float b = (kk + j < HID) ? ba1[kk + j] : 0.f;
            af[j] = (short)f2bf(fmaxf(bf2f(raw[j]) + b, 0.f));
        }
#pragma unroll
        for (int nt = 0; nt < 10; ++nt) {
            bf16x8 bf = *(const bf16x8*)(bb + nt * 16 * KP2 + k0);
            acc[nt] = __builtin_amdgcn_mfma_f32_16x16x32_bf16(af, bf, acc[nt], 0, 0, 0);
        }
    }

    float sc[4] = {0.f, 0.f, 0.f, 0.f};
#pragma unroll
    for (int nt = 0; nt < 10; ++nt) {
        const int col = nt * 16 + l15;
        const float w3 = (col < HID) ? Wa3[col] : 0.f;
        const float b2 = (col < HID) ? ba2[col] : 0.f;
#pragma unroll
        for (int i = 0; i < 4; ++i)
            sc[i] = fmaf(fmaxf(acc[nt][i] + b2, 0.f), w3, sc[i]);
    }
#pragma unroll
    for (int off = 8; off >= 1; off >>= 1)
#pragma unroll
        for (int i = 0; i < 4; ++i) sc[i] += __shfl_down(sc[i], off, 16);
    if (l15 == 0) {
        const float b3 = ba3[0];
#pragma unroll
        for (int i = 0; i < 4; ++i) attns[t0 + quad * 4 + i] = sc[i] + b3;
    }
}

// ---------------------------------------------------------------------------
// Span kernel: 32 spans/block, grid 1024. Gather-combine from bf16 P
// (XCD-L2 resident) -> h1 bf16 in LDS; layer2 MFMA; layer3 shuffle-reduce.
// ---------------------------------------------------------------------------
__global__ __launch_bounds__(256) void span_kernel(
    const unsigned short* __restrict__ Pb, const float* __restrict__ attns,
    const unsigned short* __restrict__ wp,
    const int* __restrict__ span_starts, const int* __restrict__ span_widths,
    const float* __restrict__ bs1, const float* __restrict__ bs2,
    const float* __restrict__ Ws3, const float* __restrict__ bs3,
    float* __restrict__ out)
{
    __shared__ unsigned short sHb[32][168];
    __shared__ float s_wgt[32][W_MAX];
    __shared__ int s_st[32], s_wd[32], s_bin[32];
    __shared__ float sPart[4][32];
    __shared__ float sb1[KP2];

    const int tid = threadIdx.x;
    const int n0s = blockIdx.x * 32;

    if (tid < KP2) sb1[tid] = (tid < HID) ? bs1[tid] : 0.f;
    if (tid < 32) {
        int st = span_starts[n0s + tid], wd = span_widths[n0s + tid];
        s_st[tid] = st; s_wd[tid] = wd;
        s_bin[tid] = (wd >= 1) + (wd >= 2) + (wd >= 3) + (wd >= 4) +
                     (wd >= 8) + (wd >= 16) + (wd >= 32) + (wd >= 64);
        float lg[W_MAX];
        float m = -1e30f;
#pragma unroll
        for (int w = 0; w < W_MAX; ++w)
            if (w < wd) { float a = attns[st + w]; lg[w] = a; m = fmaxf(m, a); }
        float sum = 0.f;
#pragma unroll
        for (int w = 0; w < W_MAX; ++w) {
            float e = (w < wd) ? __expf(lg[w] - m) : 0.f;
            lg[w] = e; sum += e;
        }
        float inv = 1.f / sum;
#pragma unroll
        for (int w = 0; w < W_MAX; ++w) s_wgt[tid][w] = lg[w] * inv;
    }
    __syncthreads();

    // gather-combine: 8 lanes/span, bf16x8 chunks
    {
        const unsigned short* P1b = Pb + PB_P1;
        const unsigned short* P2b = Pb + PB_P2;
        const unsigned short* P3b = Pb + PB_P3;
        const unsigned short* WEb = wp + WP_WE1;
        const int s = tid >> 3, jl = tid & 7;
        const int st = s_st[s], wd = s_wd[s];
        const size_t rs = (size_t)st * PR;
        const size_t re = (size_t)(st + wd - 1) * PR;
        const size_t rb = (size_t)s_bin[s] * PR;
        for (int c = jl; c < 20; c += 8) {
            const int j = c * 8;
            bf16x8 u1 = *(const bf16x8*)(P1b + rs + j);
            bf16x8 u2 = *(const bf16x8*)(P2b + re + j);
            bf16x8 uw = *(const bf16x8*)(WEb + rb + j);
            float acc[8];
#pragma unroll
            for (int i = 0; i < 8; ++i)
                acc[i] = bf2f(u1[i]) + bf2f(u2[i]) + bf2f(uw[i]) + sb1[j + i];
#pragma unroll
            for (int w = 0; w < W_MAX; ++w) {
                if (w < wd) {
                    float wt = s_wgt[s][w];
                    bf16x8 uv = *(const bf16x8*)(P3b + rs + (size_t)w * PR + j);
#pragma unroll
                    for (int i = 0; i < 8; ++i)
                        acc[i] = fmaf(wt, bf2f(uv[i]), acc[i]);
                }
            }
            bf16x8 pk;
#pragma unroll
            for (int i = 0; i < 8; ++i) pk[i] = (short)f2bf(fmaxf(acc[i], 0.f));
            *(bf16x8*)&sHb[s][j] = pk;
        }
    }
    __syncthreads();

    // layer2 MFMA: M=32 (2 m-tiles), N=160 (tiles 3,3,2,2 over waves)
    const int wv = tid >> 6, lane = tid & 63, l15 = lane & 15, quad = lane >> 4;
    const int nb = (wv < 2) ? wv * 3 : 6 + (wv - 2) * 2;
    const int cnt = (wv < 2) ? 3 : 2;

    f32x4 a2[2][3];
#pragma unroll
    for (int mt = 0; mt < 2; ++mt)
#pragma unroll
        for (int t = 0; t < 3; ++t)
#pragma unroll
            for (int i = 0; i < 4; ++i) a2[mt][t][i] = 0.f;

#pragma unroll
    for (int c = 0; c < 5; ++c) {
        int k0 = c * 32;
        bf16x8 af0 = *(const bf16x8*)&sHb[l15][k0 + quad * 8];
        bf16x8 af1 = *(const bf16x8*)&sHb[16 + l15][k0 + quad * 8];
#pragma unroll
        for (int t = 0; t < 3; ++t) {
            if (t < cnt) {
                bf16x8 b = *(const bf16x8*)(wp + WP_S2 +
                            (size_t)((nb + t) * 16 + l15) * KP2 + k0 + quad * 8);
                a2[0][t] = __builtin_amdgcn_mfma_f32_16x16x32_bf16(af0, b, a2[0][t], 0, 0, 0);
                a2[1][t] = __builtin_amdgcn_mfma_f32_16x16x32_bf16(af1, b, a2[1][t], 0, 0, 0);
            }
        }
    }

    float sc[2][4];
#pragma unroll
    for (int mt = 0; mt < 2; ++mt)
#pragma unroll
        for (int i = 0; i < 4; ++i) sc[mt][i] = 0.f;
#pragma unroll
    for (int t = 0; t < 3; ++t) {
        if (t < cnt) {
            int col = (nb + t) * 16 + l15;
            float w3 = (col < HID) ? Ws3[col] : 0.f;
            float b2 = (col < HID) ? bs2[col] : 0.f;
#pragma unroll
            for (int mt = 0; mt < 2; ++mt)
#pragma unroll
                for (int i = 0; i < 4; ++i)
                    sc[mt][i] = fmaf(fmaxf(a2[mt][t][i] + b2, 0.f), w3, sc[mt][i]);
        }
    }
#pragma unroll
    for (int off = 8; off >= 1; off >>= 1)
#pragma unroll
        for (int mt = 0; mt < 2; ++mt)
#pragma unroll
            for (int i = 0; i < 4; ++i)
                sc[mt][i] += __shfl_down(sc[mt][i], off, 16);
    if (l15 == 0) {
#pragma unroll
        for (int mt = 0; mt < 2; ++mt)
#pragma unroll
            for (int i = 0; i < 4; ++i)
                sPart[wv][mt * 16 + quad * 4 + i] = sc[mt][i];
    }
    __syncthreads();
    if (tid < 32)
        out[n0s + tid] = sPart[0][tid] + sPart[1][tid] + sPart[2][tid] +
                         sPart[3][tid] + bs3[0];
}

// ---------------------------------------------------------------------------
extern "C" void kernel_launch(void* const* d_in, const int* in_sizes, int n_in,
                              void* d_out, int out_size, void* d_ws, size_t ws_size,
                              hipStream_t stream)
{
    const float* states      = (const float*)d_in[0];
    const float* embeds      = (const float*)d_in[1];
    const int*   span_starts = (const int*)d_in[2];
    const int*   span_widths = (const int*)d_in[3];
    const float* Wa1 = (const float*)d_in[4];
    const float* ba1 = (const float*)d_in[5];
    const float* Wa2 = (const float*)d_in[6];
    const float* ba2 = (const float*)d_in[7];
    const float* Wa3 = (const float*)d_in[8];
    const float* ba3 = (const float*)d_in[9];
    const float* width_emb = (const float*)d_in[10];
    const float* Ws1 = (const float*)d_in[11];
    const float* bs1 = (const float*)d_in[12];
    const float* Ws2 = (const float*)d_in[13];
    const float* bs2 = (const float*)d_in[14];
    const float* Ws3 = (const float*)d_in[15];
    const float* bs3 = (const float*)d_in[16];
    float* out = (float*)d_out;

    float* ws    = (float*)d_ws;
    float* attns = ws + WS_ATTNS;
    unsigned short* Pb    = (unsigned short*)(ws + WS_PB);
    unsigned short* wpack = (unsigned short*)(ws + WS_WPACK);
    unsigned short* Sb    = (unsigned short*)(ws + WS_SB);
    unsigned short* Eb    = (unsigned short*)(ws + WS_EB);

    hipLaunchKernelGGL(prepack_kernel, dim3((PK_ITEMS + 255) / 256), dim3(256), 0, stream,
                       states, embeds, Wa1, Ws1, Wa2, Ws2, width_emb,
                       wpack, Sb, Eb);
    hipLaunchKernelGGL(token_kernel, dim3(2048), dim3(64), 0, stream,
                       Sb, Eb, wpack, Pb);
    hipLaunchKernelGGL(attn_tail_kernel, dim3(T_TOK / 16), dim3(64), 0, stream,
                       Pb + PB_P0, ba1, wpack, ba2, Wa3, ba3, attns);
    hipLaunchKernelGGL(span_kernel, dim3(N_SPAN / 32), dim3(256), 0, stream,
                       Pb, attns, wpack, span_starts, span_widths,
                       bs1, bs2, Ws3, bs3, out);
}